// Round 3
// baseline (229.316 us; speedup 1.0000x reference)
//
#include <hip/hip_runtime.h>

// Sizes fixed by the reference.
#define BB 4
#define SS 4096
#define DM 1024
#define HID 64
#define KTOP 204
static constexpr size_t PATTERN_N = (size_t)BB * SS * SS;  // 67108864

typedef float f4 __attribute__((ext_vector_type(4)));

// ---------------------------------------------------------------------------
// K1: scores[b,s] = relu(emb[b,s,:] @ W1 + b1) @ W2 + b2
// 512 blocks x 256 threads. lane = hidden unit h (64 = wave width); each wave
// owns 8 tokens. NO LDS: embedding values are wave-uniform (same for all h)
// -> uniform loads; W1[d][h] is the per-lane load, 256B/wave, L1-resident.
// ---------------------------------------------------------------------------
__global__ __launch_bounds__(256) void k1_scores(
    const float* __restrict__ emb, const float* __restrict__ W1,
    const float* __restrict__ b1, const float* __restrict__ W2,
    const float* __restrict__ b2, float* __restrict__ scores) {
  const int tid = threadIdx.x;
  const int h = tid & 63;
  const int wv = __builtin_amdgcn_readfirstlane(tid >> 6);  // wave-uniform
  const int tok0 = blockIdx.x * 32 + wv * 8;
  const float* __restrict__ eb = emb + (size_t)tok0 * DM;  // uniform base

  float acc[8];
#pragma unroll
  for (int t = 0; t < 8; ++t) acc[t] = 0.f;

  const float* __restrict__ wp = W1 + h;

#pragma unroll 1
  for (int d = 0; d < DM; d += 8) {
    float w[8];
#pragma unroll
    for (int j = 0; j < 8; ++j) w[j] = wp[(size_t)(d + j) * HID];
    f4 e0[8], e1[8];
#pragma unroll
    for (int t = 0; t < 8; ++t) {
      e0[t] = *reinterpret_cast<const f4*>(eb + (size_t)t * DM + d);
      e1[t] = *reinterpret_cast<const f4*>(eb + (size_t)t * DM + d + 4);
    }
#pragma unroll
    for (int t = 0; t < 8; ++t) {
      acc[t] = fmaf(e0[t].x, w[0], acc[t]);
      acc[t] = fmaf(e0[t].y, w[1], acc[t]);
      acc[t] = fmaf(e0[t].z, w[2], acc[t]);
      acc[t] = fmaf(e0[t].w, w[3], acc[t]);
      acc[t] = fmaf(e1[t].x, w[4], acc[t]);
      acc[t] = fmaf(e1[t].y, w[5], acc[t]);
      acc[t] = fmaf(e1[t].z, w[6], acc[t]);
      acc[t] = fmaf(e1[t].w, w[7], acc[t]);
    }
  }

  const float bb1 = b1[h];
  const float ww2 = W2[h];
  const float bb2 = b2[0];
#pragma unroll
  for (int t = 0; t < 8; ++t) {
    float s = acc[t] + bb1;
    s = s > 0.f ? s : 0.f;  // relu
    float c = s * ww2;      // per-hidden contribution
#pragma unroll
    for (int m = 32; m > 0; m >>= 1) c += __shfl_xor(c, m, 64);
    if (h == 0) scores[tok0 + t] = c + bb2;
  }
}

// ---------------------------------------------------------------------------
// K2: exact top-k by rank counting. rank(i) = #{j: s_j>s_i} + #{j<i: s_j==s_i}
// reproduces jax.lax.top_k ordering (descending, ties -> lower index first).
// 256 blocks x 256 threads: block = (batch, 64-wide i-chunk); the 4 waves
// split the j-range 4 ways, tree-combined through LDS.
// ---------------------------------------------------------------------------
__global__ __launch_bounds__(256) void k2_topk(
    const float* __restrict__ scores, float* __restrict__ out_idx) {
  __shared__ __align__(16) float sc[SS];
  __shared__ int red[256];
  const int tid = threadIdx.x;
  const int b = blockIdx.x >> 6;
  const int ic = blockIdx.x & 63;
  const float* row = scores + (size_t)b * SS;
#pragma unroll
  for (int q = 0; q < 4; ++q) {
    int f = tid + q * 256;  // float4 index
    *reinterpret_cast<f4*>(&sc[f * 4]) =
        *reinterpret_cast<const f4*>(&row[f * 4]);
  }
  __syncthreads();
  const int il = tid & 63;
  const int part = tid >> 6;  // j quarter (wave-uniform)
  const int i = ic * 64 + il;
  const float si = sc[i];
  const f4* s4 = reinterpret_cast<const f4*>(sc);
  int cnt = 0;
  for (int j4 = part * 256; j4 < part * 256 + 256; ++j4) {
    f4 v = s4[j4];  // broadcast LDS read
    int j = j4 * 4;
    cnt += (int)(v.x > si) + (int)((v.x == si) & (j + 0 < i));
    cnt += (int)(v.y > si) + (int)((v.y == si) & (j + 1 < i));
    cnt += (int)(v.z > si) + (int)((v.z == si) & (j + 2 < i));
    cnt += (int)(v.w > si) + (int)((v.w == si) & (j + 3 < i));
  }
  red[tid] = cnt;
  __syncthreads();
  if (tid < 64) {
    int tot = red[tid] + red[tid + 64] + red[tid + 128] + red[tid + 192];
    if (tot < KTOP) out_idx[b * KTOP + tot] = (float)(ic * 64 + tid);
  }
}

// ---------------------------------------------------------------------------
// K3: attention_pattern[b,i,:] = col_mask[b,:] for all i.
// 2048 blocks x 256 threads; block owns 8 rows of one batch (8 blocks/CU).
// PLAIN float4 stores (NT stores measured ~4x slower than the fill kernel's
// plain-store 7 TB/s — suspected write-combine pathology with nt flag).
// ---------------------------------------------------------------------------
__global__ __launch_bounds__(256) void k3_pattern(
    const float* __restrict__ out_idx, float* __restrict__ pat) {
  __shared__ __align__(16) float mask[SS];
  const int tid = threadIdx.x;
  const int b  = blockIdx.x >> 9;            // 512 blocks per batch
  const int r0 = (blockIdx.x & 511) * 8;
  const f4 zero = (f4){0.f, 0.f, 0.f, 0.f};
#pragma unroll
  for (int q = 0; q < 4; ++q) {
    int f = tid + q * 256;
    *reinterpret_cast<f4*>(&mask[f * 4]) = zero;
  }
  __syncthreads();
  if (tid < KTOP) {
    int c = (int)out_idx[b * KTOP + tid];
    mask[c] = 1.0f / (float)KTOP;
  }
  __syncthreads();
  const f4 m0 = *reinterpret_cast<const f4*>(&mask[(tid)*4]);
  const f4 m1 = *reinterpret_cast<const f4*>(&mask[(tid + 256) * 4]);
  const f4 m2 = *reinterpret_cast<const f4*>(&mask[(tid + 512) * 4]);
  const f4 m3 = *reinterpret_cast<const f4*>(&mask[(tid + 768) * 4]);
  for (int r = 0; r < 8; ++r) {
    f4* p4 = reinterpret_cast<f4*>(pat + ((size_t)b * SS + r0 + r) * SS);
    p4[tid]       = m0;
    p4[tid + 256] = m1;
    p4[tid + 512] = m2;
    p4[tid + 768] = m3;
  }
}

extern "C" void kernel_launch(void* const* d_in, const int* in_sizes, int n_in,
                              void* d_out, int out_size, void* d_ws,
                              size_t ws_size, hipStream_t stream) {
  const float* emb = (const float*)d_in[0];
  const float* W1  = (const float*)d_in[1];
  const float* b1  = (const float*)d_in[2];
  const float* W2  = (const float*)d_in[3];
  const float* b2  = (const float*)d_in[4];
  float* out = (float*)d_out;
  float* pat     = out;              // [B,S,S] pattern
  float* out_idx = out + PATTERN_N;  // [B,KTOP] indices as float
  // scores scratch lives in the first 64 KB of the pattern region;
  // K3 overwrites it afterwards (kernels are stream-ordered).
  float* scores = out;

  k1_scores<<<dim3((BB * SS) / 32), dim3(256), 0, stream>>>(emb, W1, b1, W2,
                                                            b2, scores);
  k2_topk<<<dim3(BB * (SS / 64)), dim3(256), 0, stream>>>(scores, out_idx);
  k3_pattern<<<dim3((BB * SS) / 8), dim3(256), 0, stream>>>(out_idx, pat);
}

// Round 4
// 145.265 us; speedup vs baseline: 1.5786x; 1.5786x over previous
//
#include <hip/hip_runtime.h>

// Sizes fixed by the reference.
#define BB 4
#define SS 4096
#define DM 1024
#define HID 64
#define KTOP 204
static constexpr size_t PATTERN_N = (size_t)BB * SS * SS;  // 67108864

typedef float f4 __attribute__((ext_vector_type(4)));

// ---------------------------------------------------------------------------
// K1: scores[b,s] = relu(emb[b,s,:] @ W1 + b1) @ W2 + b2
// 512 blocks x 256 threads; wave owns 8 tokens. lane doubles as d-offset
// (coalesced per-lane e-loads) and h (per-lane W1 loads, L1-resident).
// Cross-lane broadcast of e via v_readlane (VALU->SGPR, compile-time lane),
// feeding v_fmac with a scalar operand. No LDS pipe, no scalar-cache data.
// ---------------------------------------------------------------------------
__global__ __launch_bounds__(256) void k1_scores(
    const float* __restrict__ emb, const float* __restrict__ W1,
    const float* __restrict__ b1, const float* __restrict__ W2,
    const float* __restrict__ b2, float* __restrict__ scores) {
  const int tid = threadIdx.x;
  const int lane = tid & 63;  // d-lane for e-loads, h-lane for W1/accum
  const int wv = tid >> 6;
  const int tok0 = blockIdx.x * 32 + wv * 8;
  const float* __restrict__ eb = emb + (size_t)tok0 * DM;
  const float* __restrict__ wp = W1 + lane;  // column h = lane

  float acc[8];
#pragma unroll
  for (int t = 0; t < 8; ++t) acc[t] = 0.f;

#pragma unroll 1
  for (int d0 = 0; d0 < DM; d0 += 64) {
    float e[8];
#pragma unroll
    for (int t = 0; t < 8; ++t) e[t] = eb[(size_t)t * DM + d0 + lane];
#pragma unroll
    for (int sub = 0; sub < 4; ++sub) {
      float w[16];
#pragma unroll
      for (int j = 0; j < 16; ++j)
        w[j] = wp[(size_t)(d0 + sub * 16 + j) * HID];
#pragma unroll
      for (int j = 0; j < 16; ++j) {
        const int src = sub * 16 + j;  // compile-time lane index
#pragma unroll
        for (int t = 0; t < 8; ++t) {
          float ev = __builtin_bit_cast(
              float, __builtin_amdgcn_readlane(
                         __builtin_bit_cast(int, e[t]), src));
          acc[t] = fmaf(ev, w[j], acc[t]);
        }
      }
    }
  }

  const float bb1 = b1[lane];
  const float ww2 = W2[lane];
  const float bb2 = b2[0];
#pragma unroll
  for (int t = 0; t < 8; ++t) {
    float s = acc[t] + bb1;
    s = s > 0.f ? s : 0.f;  // relu
    float c = s * ww2;      // per-hidden contribution
#pragma unroll
    for (int m = 32; m > 0; m >>= 1) c += __shfl_xor(c, m, 64);
    if (lane == 0) scores[tok0 + t] = c + bb2;
  }
}

// ---------------------------------------------------------------------------
// K2: exact top-k by rank counting. rank(i) = #{j: s_j>s_i} + #{j<i: s_j==s_i}
// reproduces jax.lax.top_k ordering (descending, ties -> lower index first).
// 256 blocks x 256 threads: block = (batch, 64-wide i-chunk); the 4 waves
// split the j-range 4 ways, tree-combined through LDS.
// ---------------------------------------------------------------------------
__global__ __launch_bounds__(256) void k2_topk(
    const float* __restrict__ scores, float* __restrict__ out_idx) {
  __shared__ __align__(16) float sc[SS];
  __shared__ int red[256];
  const int tid = threadIdx.x;
  const int b = blockIdx.x >> 6;
  const int ic = blockIdx.x & 63;
  const float* row = scores + (size_t)b * SS;
#pragma unroll
  for (int q = 0; q < 4; ++q) {
    int f = tid + q * 256;  // float4 index
    *reinterpret_cast<f4*>(&sc[f * 4]) =
        *reinterpret_cast<const f4*>(&row[f * 4]);
  }
  __syncthreads();
  const int il = tid & 63;
  const int part = tid >> 6;  // j quarter (wave-uniform)
  const int i = ic * 64 + il;
  const float si = sc[i];
  const f4* s4 = reinterpret_cast<const f4*>(sc);
  int cnt = 0;
  for (int j4 = part * 256; j4 < part * 256 + 256; ++j4) {
    f4 v = s4[j4];  // broadcast LDS read
    int j = j4 * 4;
    cnt += (int)(v.x > si) + (int)((v.x == si) & (j + 0 < i));
    cnt += (int)(v.y > si) + (int)((v.y == si) & (j + 1 < i));
    cnt += (int)(v.z > si) + (int)((v.z == si) & (j + 2 < i));
    cnt += (int)(v.w > si) + (int)((v.w == si) & (j + 3 < i));
  }
  red[tid] = cnt;
  __syncthreads();
  if (tid < 64) {
    int tot = red[tid] + red[tid + 64] + red[tid + 128] + red[tid + 192];
    if (tot < KTOP) out_idx[b * KTOP + tot] = (float)(ic * 64 + tid);
  }
}

// ---------------------------------------------------------------------------
// K3: attention_pattern[b,i,:] = col_mask[b,:] for all i.
// 1024 blocks x 256 threads; block owns 16 rows of one batch. Nontemporal
// stores (R2 vs R3 evidence: NT ~17us, plain ~67us for the 268MB pattern —
// NT streams into L3 while plain thrashes L2 writeback).
// ---------------------------------------------------------------------------
__global__ __launch_bounds__(256) void k3_pattern(
    const float* __restrict__ out_idx, float* __restrict__ pat) {
  __shared__ __align__(16) float mask[SS];
  const int tid = threadIdx.x;
  const int b  = blockIdx.x >> 8;            // 256 blocks per batch
  const int r0 = (blockIdx.x & 255) * 16;
  const f4 zero = (f4){0.f, 0.f, 0.f, 0.f};
#pragma unroll
  for (int q = 0; q < 4; ++q) {
    int f = tid + q * 256;
    *reinterpret_cast<f4*>(&mask[f * 4]) = zero;
  }
  __syncthreads();
  if (tid < KTOP) {
    int c = (int)out_idx[b * KTOP + tid];
    mask[c] = 1.0f / (float)KTOP;
  }
  __syncthreads();
  const f4 m0 = *reinterpret_cast<const f4*>(&mask[(tid)*4]);
  const f4 m1 = *reinterpret_cast<const f4*>(&mask[(tid + 256) * 4]);
  const f4 m2 = *reinterpret_cast<const f4*>(&mask[(tid + 512) * 4]);
  const f4 m3 = *reinterpret_cast<const f4*>(&mask[(tid + 768) * 4]);
  for (int r = 0; r < 16; ++r) {
    f4* p4 = reinterpret_cast<f4*>(pat + ((size_t)b * SS + r0 + r) * SS);
    __builtin_nontemporal_store(m0, &p4[tid]);
    __builtin_nontemporal_store(m1, &p4[tid + 256]);
    __builtin_nontemporal_store(m2, &p4[tid + 512]);
    __builtin_nontemporal_store(m3, &p4[tid + 768]);
  }
}

extern "C" void kernel_launch(void* const* d_in, const int* in_sizes, int n_in,
                              void* d_out, int out_size, void* d_ws,
                              size_t ws_size, hipStream_t stream) {
  const float* emb = (const float*)d_in[0];
  const float* W1  = (const float*)d_in[1];
  const float* b1  = (const float*)d_in[2];
  const float* W2  = (const float*)d_in[3];
  const float* b2  = (const float*)d_in[4];
  float* out = (float*)d_out;
  float* pat     = out;              // [B,S,S] pattern
  float* out_idx = out + PATTERN_N;  // [B,KTOP] indices as float
  // scores scratch lives in the first 64 KB of the pattern region;
  // K3 overwrites it afterwards (kernels are stream-ordered).
  float* scores = out;

  k1_scores<<<dim3((BB * SS) / 32), dim3(256), 0, stream>>>(emb, W1, b1, W2,
                                                            b2, scores);
  k2_topk<<<dim3(BB * (SS / 64)), dim3(256), 0, stream>>>(scores, out_idx);
  k3_pattern<<<dim3((BB * SS) / 16), dim3(256), 0, stream>>>(out_idx, pat);
}